// Round 9
// baseline (831.749 us; speedup 1.0000x reference)
//
#include <hip/hip_runtime.h>

// Problem constants
constexpr int N_TOK = 8192;      // B*S
constexpr int D_IN  = 2048;
constexpr int H_OUT = 4096;
constexpr int NEXP  = 8;
constexpr float ENT_W = 0.1f;
constexpr float MAX_USAGE = 0.3f;

// GEMM tiling: 256x128 block, 8 waves (4M x 2N), BK=64, 3-slot LDS pipeline
constexpr int BM = 256;               // token-tile
constexpr int BN = 128;               // H-tile
constexpr int BK = 64;                // K-step
constexpr int NKT = D_IN / BK;        // 32 K-tiles
constexpr int TILES_H = H_OUT / BN;   // 32
constexpr int TILES_M = N_TOK / BM;   // 32 worst-case token tiles per expert
constexpr int REGION  = 8192;         // per-expert list capacity
constexpr int ASLOT = BM * BK;        // 16384 shorts (32 KB) per A slot
constexpr int BSLOT = BN * BK;        // 8192 shorts (16 KB) per B slot

typedef __attribute__((ext_vector_type(8))) short bf16x8;
typedef __attribute__((ext_vector_type(4))) float f32x4;

__device__ __forceinline__ short f2bf(float f) {
    unsigned u = __float_as_uint(f);
    u += 0x7FFF + ((u >> 16) & 1);   // RNE
    return (short)(u >> 16);
}

__device__ __forceinline__ void gload16(const void* g, void* l) {
    __builtin_amdgcn_global_load_lds(
        (const __attribute__((address_space(1))) unsigned int*)g,
        (__attribute__((address_space(3))) unsigned int*)l, 16, 0, 0);
}

// ---------------------------------------------------------------------------
// fp32 -> bf16 bulk convert (expert_w, row-major; x fused into gate)
// ---------------------------------------------------------------------------
__global__ __launch_bounds__(256) void cvt_kernel(
    const float* __restrict__ in, short* __restrict__ out, int n8)
{
    int stride = gridDim.x * 256;
    for (int i = blockIdx.x * 256 + threadIdx.x; i < n8; i += stride) {
        const float4* p = (const float4*)in + (size_t)i * 2;
        float4 a = p[0], b = p[1];
        bf16x8 v;
        v[0] = f2bf(a.x); v[1] = f2bf(a.y); v[2] = f2bf(a.z); v[3] = f2bf(a.w);
        v[4] = f2bf(b.x); v[5] = f2bf(b.y); v[6] = f2bf(b.z); v[7] = f2bf(b.w);
        *(bf16x8*)(out + (size_t)i * 8) = v;
    }
}

// ---------------------------------------------------------------------------
// Kernel 1: gating. One wave per token; fuses x -> bf16 conversion.
// ---------------------------------------------------------------------------
__global__ __launch_bounds__(256) void gate_kernel(
    const float* __restrict__ x, const float* __restrict__ gate_w,
    const float* __restrict__ gate_b, int* __restrict__ topk_idx,
    float* __restrict__ topk_w, float* __restrict__ ent_partial,
    short* __restrict__ xb)
{
    __shared__ float ent_s[4];
    const int wv = threadIdx.x >> 6;
    const int lane = threadIdx.x & 63;
    const int t = blockIdx.x * 4 + wv;

    float acc[NEXP];
#pragma unroll
    for (int e = 0; e < NEXP; ++e) acc[e] = 0.f;

    const float4* xr = (const float4*)(x + (size_t)t * D_IN);
    short* xbr = xb + (size_t)t * D_IN;
#pragma unroll
    for (int i = 0; i < D_IN / 256; ++i) {           // 8 iters
        float4 xv = xr[lane + i * 64];
        short4 s4;
        s4.x = f2bf(xv.x); s4.y = f2bf(xv.y); s4.z = f2bf(xv.z); s4.w = f2bf(xv.w);
        *(short4*)(xbr + i * 256 + lane * 4) = s4;
#pragma unroll
        for (int e = 0; e < NEXP; ++e) {
            float4 gv = ((const float4*)(gate_w + e * D_IN))[lane + i * 64];
            acc[e] += xv.x * gv.x + xv.y * gv.y + xv.z * gv.z + xv.w * gv.w;
        }
    }
#pragma unroll
    for (int e = 0; e < NEXP; ++e)
#pragma unroll
        for (int m = 32; m >= 1; m >>= 1) acc[e] += __shfl_xor(acc[e], m, 64);

    if (lane == 0) {
        float lg[NEXP], p[NEXP];
        float mx = -1e30f;
#pragma unroll
        for (int e = 0; e < NEXP; ++e) { lg[e] = acc[e] + gate_b[e]; mx = fmaxf(mx, lg[e]); }
        float s = 0.f;
#pragma unroll
        for (int e = 0; e < NEXP; ++e) { p[e] = expf(lg[e] - mx); s += p[e]; }
        float inv = 1.f / s;
        float ent = 0.f;
#pragma unroll
        for (int e = 0; e < NEXP; ++e) { p[e] *= inv; ent -= p[e] * logf(p[e] + 1e-10f); }
        int e1 = 0; float b1 = p[0];
#pragma unroll
        for (int e = 1; e < NEXP; ++e) if (p[e] > b1) { b1 = p[e]; e1 = e; }
        int e2 = (e1 == 0) ? 1 : 0; float b2 = p[e2];
#pragma unroll
        for (int e = 0; e < NEXP; ++e)
            if (e != e1 && e != ((e1 == 0) ? 1 : 0) && p[e] > b2) { b2 = p[e]; e2 = e; }
        topk_idx[2 * t]     = e1;  topk_idx[2 * t + 1] = e2;
        topk_w[2 * t]       = b1;  topk_w[2 * t + 1]   = b2;
        ent_s[wv] = ent;
    }
    __syncthreads();
    if (threadIdx.x == 0)
        ent_partial[blockIdx.x] = ent_s[0] + ent_s[1] + ent_s[2] + ent_s[3];
}

// ---------------------------------------------------------------------------
// Kernel 2: scatter. LDS-binned, fixed per-expert regions.
// ---------------------------------------------------------------------------
__global__ __launch_bounds__(256) void scatter_kernel(
    const int* __restrict__ topk_idx, const float* __restrict__ topk_w,
    int* __restrict__ cursors, int* __restrict__ tok_list,
    float* __restrict__ w_list)
{
    __shared__ int lcnt[NEXP], lbase[NEXP];
    const int tid = threadIdx.x;
    const int t = blockIdx.x * 256 + tid;
    if (tid < NEXP) lcnt[tid] = 0;
    __syncthreads();
    int e0 = topk_idx[2 * t], e1 = topk_idx[2 * t + 1];
    float w0 = topk_w[2 * t], w1 = topk_w[2 * t + 1];
    int p0 = atomicAdd(&lcnt[e0], 1);
    int p1 = atomicAdd(&lcnt[e1], 1);
    __syncthreads();
    if (tid < NEXP) lbase[tid] = atomicAdd(&cursors[tid], lcnt[tid]);
    __syncthreads();
    int d0 = e0 * REGION + lbase[e0] + p0;
    int d1 = e1 * REGION + lbase[e1] + p1;
    tok_list[d0] = t;  w_list[d0] = w0;
    tok_list[d1] = t;  w_list[d1] = w1;
}

// ---------------------------------------------------------------------------
// Kernel 3: finalize — entropy reduce + overuse penalty (counts = cursors).
// ---------------------------------------------------------------------------
__global__ __launch_bounds__(256) void finalize_kernel(
    const int* __restrict__ counts, const float* __restrict__ ent_partial,
    float* __restrict__ loss_out)
{
    __shared__ float red[256];
    float s = 0.f;
    for (int i = threadIdx.x; i < N_TOK / 4; i += 256) s += ent_partial[i];
    red[threadIdx.x] = s;
    __syncthreads();
    for (int st = 128; st > 0; st >>= 1) {
        if (threadIdx.x < st) red[threadIdx.x] += red[threadIdx.x + st];
        __syncthreads();
    }
    if (threadIdx.x == 0) {
        float loss = ENT_W * red[0] / (float)N_TOK;
        for (int e = 0; e < NEXP; ++e) {
            float r = (float)counts[e] / (float)N_TOK - MAX_USAGE;
            if (r > 0.f) loss += r;
        }
        loss_out[0] = loss;
    }
}

// ---------------------------------------------------------------------------
// Kernel 4: grouped GEMM — phase-scheduled 256x128 / BK=64 / 8 waves (4Mx2N),
// 3-slot LDS pipeline (144 KB, 1 block/CU; within-block wave role-split is
// the overlap engine, m201-style). Per K-tile: 2 phases (k2=0,1), each
//   { 8 ds_read (4 A + 4 B frags) | stage gloads for kt+2 -> SBAR ->
//     lgkm0 -> setprio(1) -> 16 MFMA -> setprio(0) -> [PH_B: vmcnt(6)] SBAR }
// Ledger: during kt we stage kt+2 (slot (kt+2)%3, free since kt-1 retired):
// 6 gloads/thread (A halves 4, B 2). At PH_B certify, outstanding =
// [kt+1:6, kt+2:6] -> vmcnt(6) certifies kt+1 with 1.5-tile cover. No
// vmcnt(0) in steady state. Swizzle: involution slot^=(row&7) on staged
// source + ds_read (r5-proven, 0 conflicts).
// ---------------------------------------------------------------------------
__global__ __launch_bounds__(512) void moe_gemm(
    const short* __restrict__ xb, const short* __restrict__ wb,
    const float* __restrict__ expert_b, const int* __restrict__ tok_list,
    const float* __restrict__ w_list, const int* __restrict__ counts,
    float* __restrict__ out)
{
    const int bid = blockIdx.x;
    const int e   = bid / (TILES_M * TILES_H);
    const int rem = bid % (TILES_M * TILES_H);
    const int tm  = rem / TILES_H;
    const int th  = rem % TILES_H;     // th inner: consecutive bids share A-tile

    const int cnt = counts[e];
    if (tm * BM >= cnt) return;
    const int valid = cnt - tm * BM;
    const int hbase = th * BN;

    __shared__ __align__(16) short A3[3 * ASLOT];   // 96 KB
    __shared__ __align__(16) short B3[3 * BSLOT];   // 48 KB
    __shared__ int   tok_s[BM];
    __shared__ float wgt_s[BM];

    const int tid = threadIdx.x;
    if (tid < BM) {
        bool v = tid < valid;
        int src = e * REGION + tm * BM + tid;
        tok_s[tid] = v ? tok_list[src] : 0;
        wgt_s[tid] = v ? w_list[src] : 0.f;
    }
    __syncthreads();

    const int lane = tid & 63;
    const int wv = tid >> 6;           // 0..7
    const int wm = wv >> 1;            // 0..3 (M)
    const int wn = wv & 1;             // 0..1 (N)
    const int rr = lane & 15, kg = lane >> 4;

    // ---- staging geometry: per half-tile (128 rows x 128B = 16 KB), flat
    // chunk f = round*512 + tid (f in 0..1023): row = f>>3, slot = f&7;
    // source slot swizzled s2 = (f&7)^(row&7); LDS dest linear (f*16B).
    // A: halves h=0,1 (rows h*128..); B: one half. 6 source ptrs/thread.
    const char* a_src[2][2];           // [half][round]
    const char* b_src[2];              // [round]
    int a_dst[2][2];                   // shorts, wave-uniform part
    int b_dst[2];
#pragma unroll
    for (int ro = 0; ro < 2; ++ro) {
        int f = ro * 512 + tid;
        int row = f >> 3;
        int s2 = (f & 7) ^ (row & 7);
#pragma unroll
        for (int h = 0; h < 2; ++h) {
            a_src[h][ro] = (const char*)(xb + (size_t)tok_s[h * 128 + row] * D_IN)
                           + s2 * 16;
            a_dst[h][ro] = h * 8192 + (ro * 512 + wv * 64) * 8;
        }
        b_src[ro] = (const char*)(wb + ((size_t)e * H_OUT + hbase + row) * D_IN)
                    + s2 * 16;
        b_dst[ro] = (ro * 512 + wv * 64) * 8;
    }

    // ---- fragment read bases (shorts). row&7 == rr&7 for all frags.
    const int Abase = (wm * 64 + rr) * 64;
    const int Bbase = (wn * 64 + rr) * 64;
    const int swz0 = (kg ^ (rr & 7)) * 8;         // k2=0
    const int swz1 = ((4 + kg) ^ (rr & 7)) * 8;   // k2=1

    f32x4 acc[4][4] = {};

#define STAGE_KT(slot)                                                     \
    {                                                                      \
        short* Aso = A3 + (slot) * ASLOT;                                  \
        short* Bso = B3 + (slot) * BSLOT;                                  \
        gload16(a_src[0][0], Aso + a_dst[0][0]); a_src[0][0] += 128;       \
        gload16(a_src[0][1], Aso + a_dst[0][1]); a_src[0][1] += 128;       \
        gload16(a_src[1][0], Aso + a_dst[1][0]); a_src[1][0] += 128;       \
        gload16(a_src[1][1], Aso + a_dst[1][1]); a_src[1][1] += 128;       \
        gload16(b_src[0],    Bso + b_dst[0]);    b_src[0]    += 128;       \
        gload16(b_src[1],    Bso + b_dst[1]);    b_src[1]    += 128;       \
    }

    // prologue: stage kt=0 (slot0) and kt=1 (slot1); certify kt0.
    STAGE_KT(0);
    STAGE_KT(1);
    asm volatile("s_waitcnt vmcnt(6)" ::: "memory");
    __builtin_amdgcn_sched_barrier(0);
    __builtin_amdgcn_s_barrier();

    for (int kt = 0; kt < NKT; ++kt) {
        const int slot = kt % 3;
        const int nslot = (kt + 2) % 3;
        const short* Ac = A3 + slot * ASLOT;
        const short* Bc = B3 + slot * BSLOT;
        const bool pre = (kt + 2 < NKT);

        bf16x8 af[4], bf_[4];

        // ======== PHASE A (k2 = 0) ========
#pragma unroll
        for (int mi = 0; mi < 4; ++mi)
            af[mi] = *(const bf16x8*)&Ac[Abase + mi * 1024 + swz0];
#pragma unroll
        for (int ni = 0; ni < 4; ++ni)
            bf_[ni] = *(const bf16x8*)&Bc[Bbase + ni * 1024 + swz0];
        if (pre) {   // stage A-halves of kt+2
            short* Aso = A3 + nslot * ASLOT;
            gload16(a_src[0][0], Aso + a_dst[0][0]); a_src[0][0] += 128;
            gload16(a_src[0][1], Aso + a_dst[0][1]); a_src[0][1] += 128;
            gload16(a_src[1][0], Aso + a_dst[1][0]); a_src[1][0] += 128;
            gload16(a_src[1][1], Aso + a_dst[1][1]); a_src[1][1] += 128;
        }
        __builtin_amdgcn_s_barrier();
        asm volatile("s_waitcnt lgkmcnt(0)" ::: "memory");
        __builtin_amdgcn_sched_barrier(0);
        __builtin_amdgcn_s_setprio(1);
#pragma unroll
        for (int mi = 0; mi < 4; ++mi)
#pragma unroll
            for (int ni = 0; ni < 4; ++ni)
                acc[mi][ni] = __builtin_amdgcn_mfma_f32_16x16x32_bf16(
                    af[mi], bf_[ni], acc[mi][ni], 0, 0, 0);
        __builtin_amdgcn_s_setprio(0);
        __builtin_amdgcn_s_barrier();

        // ======== PHASE B (k2 = 1) ========
#pragma unroll
        for (int mi = 0; mi < 4; ++mi)
            af[mi] = *(const bf16x8*)&Ac[Abase + mi * 1024 + swz1];
#pragma unroll
        for (int ni = 0; ni < 4; ++ni)
            bf_[ni] = *(const bf16x8*)&Bc[Bbase + ni * 1024 + swz1];
        if (pre) {   // stage B of kt+2
            short* Bso = B3 + nslot * BSLOT;
            gload16(b_src[0], Bso + b_dst[0]); b_src[0] += 128;
            gload16(b_src[1], Bso + b_dst[1]); b_src[1] += 128;
        }
        __builtin_amdgcn_s_barrier();
        asm volatile("s_waitcnt lgkmcnt(0)" ::: "memory");
        __builtin_amdgcn_sched_barrier(0);
        __builtin_amdgcn_s_setprio(1);
#pragma unroll
        for (int mi = 0; mi < 4; ++mi)
#pragma unroll
            for (int ni = 0; ni < 4; ++ni)
                acc[mi][ni] = __builtin_amdgcn_mfma_f32_16x16x32_bf16(
                    af[mi], bf_[ni], acc[mi][ni], 0, 0, 0);
        __builtin_amdgcn_s_setprio(0);
        // certify kt+1: outstanding = [kt+1:6, kt+2:6] -> vmcnt(6)
        if (pre) {
            asm volatile("s_waitcnt vmcnt(6)" ::: "memory");
        } else if (kt + 1 < NKT) {
            asm volatile("s_waitcnt vmcnt(0)" ::: "memory");
        }
        __builtin_amdgcn_sched_barrier(0);
        __builtin_amdgcn_s_barrier();
    }
#undef STAGE_KT

    // epilogue: C/D layout col=lane&15, row=(lane>>4)*4+i
    const float* bias = expert_b + (size_t)e * H_OUT + hbase;
#pragma unroll
    for (int mi = 0; mi < 4; ++mi) {
#pragma unroll
        for (int ni = 0; ni < 4; ++ni) {
            int col = wn * 64 + ni * 16 + rr;
            float be = bias[col];
#pragma unroll
            for (int i = 0; i < 4; ++i) {
                int r = wm * 64 + mi * 16 + kg * 4 + i;
                if (r < valid) {
                    float val = wgt_s[r] * (acc[mi][ni][i] + be);
                    atomicAdd(&out[(size_t)tok_s[r] * H_OUT + hbase + col], val);
                }
            }
        }
    }
}

// ---------------------------------------------------------------------------
// Workspace layout (<= 162 MB):
//   0        topk_idx    64 KB
//   64K      topk_w      64 KB
//   128K     cursors     64 B
//   128K+256 ent_partial 8 KB
//   160K     tok_list    256 KB  (8 regions x 8192)
//   416K     w_list      256 KB
//   1M       xb  bf16    32 MB
//   34M      wb  bf16    128 MB  (row-major)
// ---------------------------------------------------------------------------
extern "C" void kernel_launch(void* const* d_in, const int* in_sizes, int n_in,
                              void* d_out, int out_size, void* d_ws, size_t ws_size,
                              hipStream_t stream) {
    const float* x        = (const float*)d_in[0];
    const float* gate_w   = (const float*)d_in[1];
    const float* gate_b   = (const float*)d_in[2];
    const float* expert_w = (const float*)d_in[3];
    const float* expert_b = (const float*)d_in[4];
    float* out = (float*)d_out;
    char* ws = (char*)d_ws;

    int*   topk_idx    = (int*)(ws);
    float* topk_w      = (float*)(ws + (64 << 10));
    int*   cursors     = (int*)(ws + (128 << 10));
    float* ent_partial = (float*)(ws + (128 << 10) + 256);
    int*   tok_list    = (int*)(ws + (160 << 10));
    float* w_list      = (float*)(ws + (416 << 10));
    short* xb          = (short*)(ws + (1ull << 20));
    short* wb          = (short*)(ws + (34ull << 20));

    hipMemsetAsync(cursors, 0, 64, stream);
    hipMemsetAsync(d_out, 0, (size_t)out_size * sizeof(float), stream);

    gate_kernel<<<N_TOK / 4, 256, 0, stream>>>(x, gate_w, gate_b, topk_idx,
                                               topk_w, ent_partial, xb);
    cvt_kernel<<<4096, 256, 0, stream>>>(expert_w, wb, (NEXP * H_OUT * D_IN) / 8);
    scatter_kernel<<<N_TOK / 256, 256, 0, stream>>>(topk_idx, topk_w, cursors,
                                                    tok_list, w_list);
    finalize_kernel<<<1, 256, 0, stream>>>(cursors, ent_partial,
                                           out + (size_t)N_TOK * H_OUT);
    moe_gemm<<<NEXP * TILES_M * TILES_H, 512, 0, stream>>>(
        xb, wb, expert_b, tok_list, w_list, cursors, out);
}

// Round 10
// 704.065 us; speedup vs baseline: 1.1814x; 1.1814x over previous
//
#include <hip/hip_runtime.h>

// Problem constants
constexpr int N_TOK = 8192;      // B*S
constexpr int D_IN  = 2048;
constexpr int H_OUT = 4096;
constexpr int NEXP  = 8;
constexpr float ENT_W = 0.1f;
constexpr float MAX_USAGE = 0.3f;

// GEMM tiling: 128x128 tile, BK=32, 3 LDS slots -> 49 KB -> 3 blocks/CU
constexpr int TM = 128;               // token-tile
constexpr int TH = 128;               // H-tile
constexpr int BK = 32;                // K-step (64 bytes bf16 per row)
constexpr int NKT = D_IN / BK;        // 64 K-tiles
constexpr int TILES_H = H_OUT / TH;   // 32
constexpr int TM_MAX  = N_TOK / TM;   // 64 worst-case token tiles per expert
constexpr int REGION  = 8192;         // per-expert list capacity
constexpr int BUFSZ   = TM * BK;      // shorts per LDS slot (4096 = 8 KB)

typedef __attribute__((ext_vector_type(8))) short bf16x8;
typedef __attribute__((ext_vector_type(4))) float f32x4;

__device__ __forceinline__ short f2bf(float f) {
    unsigned u = __float_as_uint(f);
    u += 0x7FFF + ((u >> 16) & 1);   // RNE
    return (short)(u >> 16);
}

__device__ __forceinline__ void gload16(const void* g, void* l) {
    __builtin_amdgcn_global_load_lds(
        (const __attribute__((address_space(1))) unsigned int*)g,
        (__attribute__((address_space(3))) unsigned int*)l, 16, 0, 0);
}

// ---------------------------------------------------------------------------
// fp32 -> bf16 bulk convert (expert_w, plain row-major; x fused into gate)
// ---------------------------------------------------------------------------
__global__ __launch_bounds__(256) void cvt_kernel(
    const float* __restrict__ in, short* __restrict__ out, int n8)
{
    int stride = gridDim.x * 256;
    for (int i = blockIdx.x * 256 + threadIdx.x; i < n8; i += stride) {
        const float4* p = (const float4*)in + (size_t)i * 2;
        float4 a = p[0], b = p[1];
        bf16x8 v;
        v[0] = f2bf(a.x); v[1] = f2bf(a.y); v[2] = f2bf(a.z); v[3] = f2bf(a.w);
        v[4] = f2bf(b.x); v[5] = f2bf(b.y); v[6] = f2bf(b.z); v[7] = f2bf(b.w);
        *(bf16x8*)(out + (size_t)i * 8) = v;
    }
}

// ---------------------------------------------------------------------------
// Kernel 1: gating. One wave per token; fuses x -> bf16 conversion.
// ---------------------------------------------------------------------------
__global__ __launch_bounds__(256) void gate_kernel(
    const float* __restrict__ x, const float* __restrict__ gate_w,
    const float* __restrict__ gate_b, int* __restrict__ topk_idx,
    float* __restrict__ topk_w, float* __restrict__ ent_partial,
    short* __restrict__ xb)
{
    __shared__ float ent_s[4];
    const int wv = threadIdx.x >> 6;
    const int lane = threadIdx.x & 63;
    const int t = blockIdx.x * 4 + wv;

    float acc[NEXP];
#pragma unroll
    for (int e = 0; e < NEXP; ++e) acc[e] = 0.f;

    const float4* xr = (const float4*)(x + (size_t)t * D_IN);
    short* xbr = xb + (size_t)t * D_IN;
#pragma unroll
    for (int i = 0; i < D_IN / 256; ++i) {           // 8 iters
        float4 xv = xr[lane + i * 64];
        short4 s4;
        s4.x = f2bf(xv.x); s4.y = f2bf(xv.y); s4.z = f2bf(xv.z); s4.w = f2bf(xv.w);
        *(short4*)(xbr + i * 256 + lane * 4) = s4;
#pragma unroll
        for (int e = 0; e < NEXP; ++e) {
            float4 gv = ((const float4*)(gate_w + e * D_IN))[lane + i * 64];
            acc[e] += xv.x * gv.x + xv.y * gv.y + xv.z * gv.z + xv.w * gv.w;
        }
    }
#pragma unroll
    for (int e = 0; e < NEXP; ++e)
#pragma unroll
        for (int m = 32; m >= 1; m >>= 1) acc[e] += __shfl_xor(acc[e], m, 64);

    if (lane == 0) {
        float lg[NEXP], p[NEXP];
        float mx = -1e30f;
#pragma unroll
        for (int e = 0; e < NEXP; ++e) { lg[e] = acc[e] + gate_b[e]; mx = fmaxf(mx, lg[e]); }
        float s = 0.f;
#pragma unroll
        for (int e = 0; e < NEXP; ++e) { p[e] = expf(lg[e] - mx); s += p[e]; }
        float inv = 1.f / s;
        float ent = 0.f;
#pragma unroll
        for (int e = 0; e < NEXP; ++e) { p[e] *= inv; ent -= p[e] * logf(p[e] + 1e-10f); }
        int e1 = 0; float b1 = p[0];
#pragma unroll
        for (int e = 1; e < NEXP; ++e) if (p[e] > b1) { b1 = p[e]; e1 = e; }
        int e2 = (e1 == 0) ? 1 : 0; float b2 = p[e2];
#pragma unroll
        for (int e = 0; e < NEXP; ++e)
            if (e != e1 && e != ((e1 == 0) ? 1 : 0) && p[e] > b2) { b2 = p[e]; e2 = e; }
        topk_idx[2 * t]     = e1;  topk_idx[2 * t + 1] = e2;
        topk_w[2 * t]       = b1;  topk_w[2 * t + 1]   = b2;
        ent_s[wv] = ent;
    }
    __syncthreads();
    if (threadIdx.x == 0)
        ent_partial[blockIdx.x] = ent_s[0] + ent_s[1] + ent_s[2] + ent_s[3];
}

// ---------------------------------------------------------------------------
// Kernel 2: scatter. LDS-binned, fixed per-expert regions.
// ---------------------------------------------------------------------------
__global__ __launch_bounds__(256) void scatter_kernel(
    const int* __restrict__ topk_idx, const float* __restrict__ topk_w,
    int* __restrict__ cursors, int* __restrict__ tok_list,
    float* __restrict__ w_list)
{
    __shared__ int lcnt[NEXP], lbase[NEXP];
    const int tid = threadIdx.x;
    const int t = blockIdx.x * 256 + tid;
    if (tid < NEXP) lcnt[tid] = 0;
    __syncthreads();
    int e0 = topk_idx[2 * t], e1 = topk_idx[2 * t + 1];
    float w0 = topk_w[2 * t], w1 = topk_w[2 * t + 1];
    int p0 = atomicAdd(&lcnt[e0], 1);
    int p1 = atomicAdd(&lcnt[e1], 1);
    __syncthreads();
    if (tid < NEXP) lbase[tid] = atomicAdd(&cursors[tid], lcnt[tid]);
    __syncthreads();
    int d0 = e0 * REGION + lbase[e0] + p0;
    int d1 = e1 * REGION + lbase[e1] + p1;
    tok_list[d0] = t;  w_list[d0] = w0;
    tok_list[d1] = t;  w_list[d1] = w1;
}

// ---------------------------------------------------------------------------
// Kernel 3: finalize — entropy reduce + overuse penalty (counts = cursors).
// ---------------------------------------------------------------------------
__global__ __launch_bounds__(256) void finalize_kernel(
    const int* __restrict__ counts, const float* __restrict__ ent_partial,
    float* __restrict__ loss_out)
{
    __shared__ float red[256];
    float s = 0.f;
    for (int i = threadIdx.x; i < N_TOK / 4; i += 256) s += ent_partial[i];
    red[threadIdx.x] = s;
    __syncthreads();
    for (int st = 128; st > 0; st >>= 1) {
        if (threadIdx.x < st) red[threadIdx.x] += red[threadIdx.x + st];
        __syncthreads();
    }
    if (threadIdx.x == 0) {
        float loss = ENT_W * red[0] / (float)N_TOK;
        for (int e = 0; e < NEXP; ++e) {
            float r = (float)counts[e] / (float)N_TOK - MAX_USAGE;
            if (r > 0.f) loss += r;
        }
        loss_out[0] = loss;
    }
}

// ---------------------------------------------------------------------------
// Kernel 4: grouped GEMM — r8's proven 128x128/BK=32 depth-2 counted pipeline
// with a THIRD LDS slot to delete the mid-tile WAR barrier:
//   tile t (slot t%3):
//     stage tile t+2 -> slot (t+2)%3   [== slot (t-1)%3: all waves finished
//                                       reading it before the end-of-(t-1)
//                                       barrier -> no WAR, no extra barrier]
//     8 ds_read frags from slot t; lgkmcnt(0); 16 MFMA;
//     vmcnt(4) certifies tile t+1 (issued a full tile ago, ~2-tile cover);
//     ONE s_barrier.
// 49 KB LDS -> 3 blocks/CU (12 waves). Swizzle as r8 (0 conflicts measured).
// ---------------------------------------------------------------------------
__global__ __launch_bounds__(256, 3) void moe_gemm(
    const short* __restrict__ xb, const short* __restrict__ wb,
    const float* __restrict__ expert_b, const int* __restrict__ tok_list,
    const float* __restrict__ w_list, const int* __restrict__ counts,
    float* __restrict__ out)
{
    const int bid = blockIdx.x;
    const int e   = bid / (TM_MAX * TILES_H);
    const int rem = bid % (TM_MAX * TILES_H);
    const int tm  = rem / TILES_H;
    const int th  = rem % TILES_H;     // th inner: consecutive bids share A-tile

    const int cnt = counts[e];
    if (tm * TM >= cnt) return;
    const int valid = cnt - tm * TM;
    const int hbase = th * TH;

    __shared__ __align__(16) short A_s[3][BUFSZ];   // 3 x 8 KB
    __shared__ __align__(16) short B_s[3][BUFSZ];   // 3 x 8 KB
    __shared__ int   tok_s[TM];
    __shared__ float wgt_s[TM];

    const int tid = threadIdx.x;
    if (tid < TM) {
        bool v = tid < valid;
        int src = e * REGION + tm * TM + tid;
        tok_s[tid] = v ? tok_list[src] : 0;
        wgt_s[tid] = v ? w_list[src] : 0.f;
    }
    __syncthreads();

    const int lane = tid & 63;
    const int wv = tid >> 6;

    // staging: 8 x 1KB chunks per operand-tile; wave wv owns chunks wv*2+j.
    // chunk c covers rows c*16..c*16+15; lane l -> row c*16+(l>>2),
    // source slot (l&3)^((l>>3)&3) (involution; (row>>1)&3 == (l>>3)&3).
    const char* asrc[2];
    const char* bsrc[2];
    int dst_off[2];                    // shorts, wave-uniform (+lane*16B by HW)
#pragma unroll
    for (int j = 0; j < 2; ++j) {
        int c = wv * 2 + j;
        int r = c * 16 + (lane >> 2);
        int s2 = (lane & 3) ^ ((lane >> 3) & 3);
        asrc[j] = (const char*)(xb + (size_t)tok_s[r] * D_IN) + s2 * 16;
        bsrc[j] = (const char*)(wb + ((size_t)e * H_OUT + hbase + r) * D_IN) + s2 * 16;
        dst_off[j] = c * 512;
    }

    const int rr = lane & 15, kg = lane >> 4;
    const int wr = wv >> 1, wc = wv & 1;

    // fragment LDS offsets (shorts), swizzled to match staging involution
    int aoff[4], boff[4];
#pragma unroll
    for (int mi = 0; mi < 4; ++mi) {
        int row = wr * 64 + mi * 16 + rr;
        aoff[mi] = row * 32 + (kg ^ ((row >> 1) & 3)) * 8;
        int rowb = wc * 64 + mi * 16 + rr;
        boff[mi] = rowb * 32 + (kg ^ ((rowb >> 1) & 3)) * 8;
    }

    f32x4 acc[4][4] = {};

#define STAGE_KT(slot)                                                     \
    {                                                                      \
        short* Aso = (short*)A_s[slot];                                    \
        short* Bso = (short*)B_s[slot];                                    \
        gload16(asrc[0], Aso + dst_off[0]); asrc[0] += BK * 2;             \
        gload16(bsrc[0], Bso + dst_off[0]); bsrc[0] += BK * 2;             \
        gload16(asrc[1], Aso + dst_off[1]); asrc[1] += BK * 2;             \
        gload16(bsrc[1], Bso + dst_off[1]); bsrc[1] += BK * 2;             \
    }

    // prologue: stage K-tiles 0 (slot0) and 1 (slot1); certify tile 0 only.
    STAGE_KT(0);
    STAGE_KT(1);
    asm volatile("s_waitcnt vmcnt(4)" ::: "memory");   // tile 0 landed
    __builtin_amdgcn_sched_barrier(0);
    __builtin_amdgcn_s_barrier();

    for (int kt = 0; kt < NKT; ++kt) {
        const int slot = kt % 3;
        const int nslot = (kt + 2) % 3;
        const short* Ac = A_s[slot];
        const short* Bc = B_s[slot];
        const bool pre = (kt + 2 < NKT);

        // stage tile kt+2 first (slot free since end of tile kt-1; VMEM
        // issued early, ~2 tiles of cover before its certify)
        if (pre) STAGE_KT(nslot);

        // consume current tile into registers
        bf16x8 af[4], bv[4];
#pragma unroll
        for (int mi = 0; mi < 4; ++mi) af[mi] = *(const bf16x8*)&Ac[aoff[mi]];
#pragma unroll
        for (int ni = 0; ni < 4; ++ni) bv[ni] = *(const bf16x8*)&Bc[boff[ni]];
        asm volatile("s_waitcnt lgkmcnt(0)" ::: "memory");
        __builtin_amdgcn_sched_barrier(0);

        __builtin_amdgcn_s_setprio(1);
#pragma unroll
        for (int mi = 0; mi < 4; ++mi)
#pragma unroll
            for (int ni = 0; ni < 4; ++ni)
                acc[mi][ni] = __builtin_amdgcn_mfma_f32_16x16x32_bf16(
                    af[mi], bv[ni], acc[mi][ni], 0, 0, 0);
        __builtin_amdgcn_s_setprio(0);

        // certify tile kt+1 (issued one full tile ago); deep prefetch
        // (kt+2, 4 loads) stays in flight.
        if (pre) {
            asm volatile("s_waitcnt vmcnt(4)" ::: "memory");
        } else if (kt + 1 < NKT) {
            asm volatile("s_waitcnt vmcnt(0)" ::: "memory");
        }
        __builtin_amdgcn_sched_barrier(0);
        __builtin_amdgcn_s_barrier();   // single barrier: slot kt readable
                                        // is done; slot kt+1 certified block-wide
    }
#undef STAGE_KT

    // epilogue: C/D layout col=lane&15, row=(lane>>4)*4+i
    const float* bias = expert_b + (size_t)e * H_OUT + hbase;
#pragma unroll
    for (int mi = 0; mi < 4; ++mi) {
#pragma unroll
        for (int ni = 0; ni < 4; ++ni) {
            int col = wc * 64 + ni * 16 + rr;
            float be = bias[col];
#pragma unroll
            for (int i = 0; i < 4; ++i) {
                int r = wr * 64 + mi * 16 + kg * 4 + i;
                if (r < valid) {
                    float val = wgt_s[r] * (acc[mi][ni][i] + be);
                    atomicAdd(&out[(size_t)tok_s[r] * H_OUT + hbase + col], val);
                }
            }
        }
    }
}

// ---------------------------------------------------------------------------
// Workspace layout (<= 162 MB):
//   0        topk_idx    64 KB
//   64K      topk_w      64 KB
//   128K     cursors     64 B
//   128K+256 ent_partial 8 KB
//   160K     tok_list    256 KB  (8 regions x 8192)
//   416K     w_list      256 KB
//   1M       xb  bf16    32 MB
//   34M      wb  bf16    128 MB  (row-major)
// ---------------------------------------------------------------------------
extern "C" void kernel_launch(void* const* d_in, const int* in_sizes, int n_in,
                              void* d_out, int out_size, void* d_ws, size_t ws_size,
                              hipStream_t stream) {
    const float* x        = (const float*)d_in[0];
    const float* gate_w   = (const float*)d_in[1];
    const float* gate_b   = (const float*)d_in[2];
    const float* expert_w = (const float*)d_in[3];
    const float* expert_b = (const float*)d_in[4];
    float* out = (float*)d_out;
    char* ws = (char*)d_ws;

    int*   topk_idx    = (int*)(ws);
    float* topk_w      = (float*)(ws + (64 << 10));
    int*   cursors     = (int*)(ws + (128 << 10));
    float* ent_partial = (float*)(ws + (128 << 10) + 256);
    int*   tok_list    = (int*)(ws + (160 << 10));
    float* w_list      = (float*)(ws + (416 << 10));
    short* xb          = (short*)(ws + (1ull << 20));
    short* wb          = (short*)(ws + (34ull << 20));

    hipMemsetAsync(cursors, 0, 64, stream);
    hipMemsetAsync(d_out, 0, (size_t)out_size * sizeof(float), stream);

    gate_kernel<<<N_TOK / 4, 256, 0, stream>>>(x, gate_w, gate_b, topk_idx,
                                               topk_w, ent_partial, xb);
    cvt_kernel<<<4096, 256, 0, stream>>>(expert_w, wb, (NEXP * H_OUT * D_IN) / 8);
    scatter_kernel<<<N_TOK / 256, 256, 0, stream>>>(topk_idx, topk_w, cursors,
                                                    tok_list, w_list);
    finalize_kernel<<<1, 256, 0, stream>>>(cursors, ent_partial,
                                           out + (size_t)N_TOK * H_OUT);
    moe_gemm<<<NEXP * TM_MAX * TILES_H, 256, 0, stream>>>(
        xb, wb, expert_b, tok_list, w_list, cursors, out);
}